// Round 1
// baseline (393.385 us; speedup 1.0000x reference)
//
#include <hip/hip_runtime.h>

#define H 384
#define W 384
#define HWSZ (H * W)
#define NB 16
#define ND 2048
#define DD 256

// workspace byte offsets (all 256-aligned)
#define OFF_RESP  256
#define OFF_CVAL  9437440
#define OFF_CPOS  9584896
#define OFF_DESCB 9732352
#define OFF_INV   26509568

__device__ __forceinline__ int clampi(int v) { return v < 0 ? 0 : (v > 383 ? 383 : v); }
__device__ __forceinline__ int refl(int v) { return v < 0 ? -v : (v >= 384 ? 766 - v : v); }

__device__ __forceinline__ unsigned short f2bf(float f) {
  unsigned u = __float_as_uint(f);
  return (unsigned short)((u + 0x7FFFu + ((u >> 16) & 1u)) >> 16);
}

// ---------------------------------------------------------------------------
// Fused: grayscale -> sobel(edge pad) -> products -> separable 7x7 gauss
// (reflect pad) -> GFTT min-eigenvalue response. One 32x32 output tile/block.
// ---------------------------------------------------------------------------
__global__ __launch_bounds__(256) void resp_kernel(const float* __restrict__ imgs,
                                                   float* __restrict__ resp) {
  const float GW[7] = {0.0044330482f, 0.0540055826f, 0.2420362294f, 0.3990502160f,
                       0.2420362294f, 0.0540055826f, 0.0044330482f};
  __shared__ float gl[40][41];
  __shared__ float p0[38][39], p1[38][39], p2[38][39];
  __shared__ float t0[38][33], t1[38][33], t2[38][33];

  int bid = blockIdx.x;
  int b = bid / 144;
  int t = bid % 144;
  int Y0 = (t / 12) * 32, X0 = (t % 12) * 32;
  const float* ib = imgs + (size_t)b * 3 * HWSZ;

  // gray tile with 4-halo, edge-clamped (clamp also serves sobel's edge pad)
  for (int i = threadIdx.x; i < 1600; i += 256) {
    int r = i / 40, c = i % 40;
    int gy = clampi(Y0 - 4 + r), gx = clampi(X0 - 4 + c);
    const float* p = ib + gy * W + gx;
    gl[r][c] = 0.299f * p[0] + 0.587f * p[HWSZ] + 0.114f * p[2 * HWSZ];
  }
  __syncthreads();

  // structure-tensor products at reflect-mapped coordinates (handles gauss pad)
  for (int i = threadIdx.x; i < 1444; i += 256) {
    int r = i / 38, c = i % 38;
    int py = refl(Y0 - 3 + r), px = refl(X0 - 3 + c);
    int ym = clampi(py - 1) - (Y0 - 4), y0 = py - (Y0 - 4), yp = clampi(py + 1) - (Y0 - 4);
    int xm = clampi(px - 1) - (X0 - 4), x0 = px - (X0 - 4), xp = clampi(px + 1) - (X0 - 4);
    float a = gl[ym][xm], bb = gl[ym][x0], cc = gl[ym][xp];
    float d = gl[y0][xm], e = gl[y0][xp];
    float f = gl[yp][xm], g = gl[yp][x0], h = gl[yp][xp];
    float dx = 0.125f * ((cc - a) + 2.f * (e - d) + (h - f));
    float dy = 0.125f * ((f - a) + 2.f * (g - bb) + (h - cc));
    p0[r][c] = dx * dx;
    p1[r][c] = dy * dy;
    p2[r][c] = dx * dy;
  }
  __syncthreads();

  // horizontal gaussian
  for (int i = threadIdx.x; i < 1216; i += 256) {
    int r = i / 32, c = i % 32;
    float s0 = 0.f, s1 = 0.f, s2 = 0.f;
#pragma unroll
    for (int j = 0; j < 7; j++) {
      s0 += GW[j] * p0[r][c + j];
      s1 += GW[j] * p1[r][c + j];
      s2 += GW[j] * p2[r][c + j];
    }
    t0[r][c] = s0; t1[r][c] = s1; t2[r][c] = s2;
  }
  __syncthreads();

  // vertical gaussian + GFTT response
  for (int i = threadIdx.x; i < 1024; i += 256) {
    int r = i / 32, c = i % 32;
    float s0 = 0.f, s1 = 0.f, s2 = 0.f;
#pragma unroll
    for (int j = 0; j < 7; j++) {
      s0 += GW[j] * t0[r + j][c];
      s1 += GW[j] * t1[r + j][c];
      s2 += GW[j] * t2[r + j][c];
    }
    float tr = s0 + s1;
    float det = s0 * s1 - s2 * s2;
    float disc = tr * tr - 4.f * det;
    float rv = 0.5f * (tr - sqrtf(fabsf(disc)));
    resp[(size_t)b * HWSZ + (Y0 + r) * W + (X0 + c)] = rv;
  }
}

// ---------------------------------------------------------------------------
// 5x5 NMS (-inf border) + per-8x8-block max candidate extraction.
// 64x64 tile per block; one (val,pos) candidate slot per 8x8 block.
// ---------------------------------------------------------------------------
__global__ __launch_bounds__(256) void nms_kernel(const float* __restrict__ resp,
                                                  float* __restrict__ cval,
                                                  unsigned* __restrict__ cpos) {
  __shared__ float rl[68][69];
  __shared__ float nl[64][65];
  int bid = blockIdx.x;
  int b = bid / 36;
  int t = bid % 36;
  int Y0 = (t / 6) * 64, X0 = (t % 6) * 64;
  const float* rb = resp + (size_t)b * HWSZ;

  for (int i = threadIdx.x; i < 68 * 68; i += 256) {
    int r = i / 68, c = i % 68;
    int gy = Y0 - 2 + r, gx = X0 - 2 + c;
    float v = -INFINITY;
    if (gy >= 0 && gy < H && gx >= 0 && gx < W) v = rb[gy * W + gx];
    rl[r][c] = v;
  }
  __syncthreads();

  for (int i = threadIdx.x; i < 4096; i += 256) {
    int r = i / 64, c = i % 64;
    float m = -INFINITY;
#pragma unroll
    for (int dr = 0; dr < 5; dr++)
#pragma unroll
      for (int dc = 0; dc < 5; dc++) m = fmaxf(m, rl[r + dr][c + dc]);
    float v = rl[r + 2][c + 2];
    nl[r][c] = (v == m) ? v : 0.f;
  }
  __syncthreads();

  if (threadIdx.x < 64) {
    int bi = threadIdx.x / 8, bj = threadIdx.x % 8;
    float bv = 0.f;
    unsigned bp = 0;
    for (int rr = 0; rr < 8; rr++)
      for (int cc = 0; cc < 8; cc++) {
        float v = nl[bi * 8 + rr][bj * 8 + cc];
        if (v > bv) { bv = v; bp = (unsigned)((Y0 + bi * 8 + rr) * W + (X0 + bj * 8 + cc)); }
      }
    int ci = b * 2304 + (Y0 / 8 + bi) * 48 + (X0 / 8 + bj);
    cval[ci] = bv;
    cpos[ci] = bp;
  }
}

// ---------------------------------------------------------------------------
// Per-batch top-200 (bitonic sort of 4096 packed keys) -> sum scores_dense at
// selected positive positions -> acc[1]. Key = valbits<<32 | ~pos (lower pos
// wins ties, matching jax top_k).
// ---------------------------------------------------------------------------
__global__ __launch_bounds__(512) void topk_kernel(const float* __restrict__ cval,
                                                   const unsigned* __restrict__ cpos,
                                                   const float* __restrict__ sd,
                                                   float* __restrict__ acc) {
  __shared__ unsigned long long keys[4096];
  __shared__ float r8[8];
  int b = blockIdx.x;
  for (int i = threadIdx.x; i < 4096; i += 512) {
    unsigned long long k = 0ull;
    if (i < 2304) {
      float v = cval[b * 2304 + i];
      if (v > 0.f)
        k = ((unsigned long long)__float_as_uint(v) << 32) |
            (unsigned long long)(0xFFFFFFFFu - cpos[b * 2304 + i]);
    }
    keys[i] = k;
  }
  __syncthreads();
  for (int kk = 2; kk <= 4096; kk <<= 1) {
    for (int j = kk >> 1; j > 0; j >>= 1) {
      for (int i = threadIdx.x; i < 4096; i += 512) {
        int ixj = i ^ j;
        if (ixj > i) {
          unsigned long long a = keys[i], c = keys[ixj];
          bool up = ((i & kk) == 0);
          if (up ? (a > c) : (a < c)) { keys[i] = c; keys[ixj] = a; }
        }
      }
      __syncthreads();
    }
  }
  // ascending sort: top-200 are the last 200 entries
  float s = 0.f;
  if (threadIdx.x < 200) {
    unsigned long long k = keys[4095 - threadIdx.x];
    if ((k >> 32) != 0ull) {
      unsigned p = 0xFFFFFFFFu - (unsigned)(k & 0xFFFFFFFFull);
      s = sd[(size_t)b * HWSZ + p];
    }
  }
  for (int off = 32; off; off >>= 1) s += __shfl_down(s, off, 64);
  if ((threadIdx.x & 63) == 0) r8[threadIdx.x >> 6] = s;
  __syncthreads();
  if (threadIdx.x == 0) {
    float tt = 0.f;
    for (int i = 0; i < 8; i++) tt += r8[i];
    atomicAdd(acc + 1, tt);
  }
}

// ---------------------------------------------------------------------------
// Sum of softplus(scores_dense) -> acc[0]
// ---------------------------------------------------------------------------
__global__ __launch_bounds__(256) void softplus_kernel(const float4* __restrict__ sd,
                                                       float* __restrict__ acc) {
  int idx = blockIdx.x * 256 + threadIdx.x;  // exactly 589824 float4s
  float4 v = sd[idx];
  float s = fmaxf(v.x, 0.f) + log1pf(expf(-fabsf(v.x))) +
            fmaxf(v.y, 0.f) + log1pf(expf(-fabsf(v.y))) +
            fmaxf(v.z, 0.f) + log1pf(expf(-fabsf(v.z))) +
            fmaxf(v.w, 0.f) + log1pf(expf(-fabsf(v.w)));
  for (int off = 32; off; off >>= 1) s += __shfl_down(s, off, 64);
  if ((threadIdx.x & 63) == 0) atomicAdd(acc + 0, s);
}

// ---------------------------------------------------------------------------
// Descriptor prep: fp32 -> bf16 copy + per-row inverse norm (fp32 norms).
// One wave per 256-float row.
// ---------------------------------------------------------------------------
__global__ __launch_bounds__(256) void prep_desc_kernel(const float* __restrict__ desc,
                                                        unsigned short* __restrict__ descB,
                                                        float* __restrict__ invn) {
  int wave = threadIdx.x >> 6, lane = threadIdx.x & 63;
  int row = blockIdx.x * 4 + wave;
  const float4* src = (const float4*)(desc + (size_t)row * DD);
  float4 v = src[lane];
  ushort4 u;
  u.x = f2bf(v.x); u.y = f2bf(v.y); u.z = f2bf(v.z); u.w = f2bf(v.w);
  ((ushort4*)(descB + (size_t)row * DD))[lane] = u;
  float ss = v.x * v.x + v.y * v.y + v.z * v.z + v.w * v.w;
  for (int off = 32; off; off >>= 1) ss += __shfl_down(ss, off, 64);
  if (lane == 0) invn[row] = 1.f / fmaxf(sqrtf(ss), 1e-4f);
}

// ---------------------------------------------------------------------------
// Symmetric batched GEMM (A·A^T) with fused relu-sum epilogue.
// 128x128 tiles, BK=64, 16x16x32 bf16 MFMA, global_load_lds width-16 staging.
// Only upper-triangular tile pairs (ti<=tj), weight 2 off-diagonal.
// ---------------------------------------------------------------------------
typedef __bf16 bf16x8 __attribute__((ext_vector_type(8)));
typedef float f32x4 __attribute__((ext_vector_type(4)));

__device__ __forceinline__ void load_lds16(const void* g, void* l) {
  __builtin_amdgcn_global_load_lds((const __attribute__((address_space(1))) void*)g,
                                   (__attribute__((address_space(3))) void*)l, 16, 0, 0);
}

__global__ __launch_bounds__(256) void gemm_relu_kernel(const unsigned short* __restrict__ descB,
                                                        const float* __restrict__ invn,
                                                        float* __restrict__ acc) {
  int bx = blockIdx.x;
  int batch = bx / 136;
  int rem = bx % 136;
  int ti = 0, rowlen = 16;
  while (rem >= rowlen) { rem -= rowlen; rowlen--; ti++; }
  int tj = ti + rem;

  const unsigned short* Ab = descB + (size_t)batch * ND * DD;
  const float* inv = invn + batch * ND;
  int I0 = ti * 128, J0 = tj * 128;

  __shared__ unsigned short lA[128 * 64];
  __shared__ unsigned short lB[128 * 64];
  __shared__ float r4[4];

  int tid = threadIdx.x;
  int wave = tid >> 6, lane = tid & 63;
  int rm = lane & 15, kq = lane >> 4;
  int wr = wave >> 1, wc = wave & 1;
  int lrow = lane >> 3, lcol = (lane & 7) * 8;

  f32x4 accf[4][4];
#pragma unroll
  for (int m = 0; m < 4; m++)
#pragma unroll
    for (int n = 0; n < 4; n++) accf[m][n] = (f32x4){0.f, 0.f, 0.f, 0.f};

  for (int k0 = 0; k0 < DD; k0 += 64) {
#pragma unroll
    for (int q = 0; q < 4; q++) {
      int chunk = wave * 4 + q;
      load_lds16(Ab + (size_t)(I0 + chunk * 8 + lrow) * DD + k0 + lcol, lA + chunk * 512);
      load_lds16(Ab + (size_t)(J0 + chunk * 8 + lrow) * DD + k0 + lcol, lB + chunk * 512);
    }
    __syncthreads();
#pragma unroll
    for (int kk = 0; kk < 64; kk += 32) {
      bf16x8 af[4], bfr[4];
      int koff = kk + kq * 8;
#pragma unroll
      for (int m = 0; m < 4; m++)
        af[m] = *reinterpret_cast<const bf16x8*>(lA + (wr * 64 + m * 16 + rm) * 64 + koff);
#pragma unroll
      for (int n = 0; n < 4; n++)
        bfr[n] = *reinterpret_cast<const bf16x8*>(lB + (wc * 64 + n * 16 + rm) * 64 + koff);
#pragma unroll
      for (int m = 0; m < 4; m++)
#pragma unroll
        for (int n = 0; n < 4; n++)
          accf[m][n] = __builtin_amdgcn_mfma_f32_16x16x32_bf16(af[m], bfr[n], accf[m][n], 0, 0, 0);
    }
    __syncthreads();
  }

  float wgt = (ti == tj) ? 1.f : 2.f;
  float invC[4];
#pragma unroll
  for (int n = 0; n < 4; n++) invC[n] = inv[J0 + wc * 64 + n * 16 + rm];
  float psum = 0.f;
#pragma unroll
  for (int m = 0; m < 4; m++) {
#pragma unroll
    for (int r = 0; r < 4; r++) {
      float invR = inv[I0 + wr * 64 + m * 16 + kq * 4 + r];
#pragma unroll
      for (int n = 0; n < 4; n++) psum += fmaxf(accf[m][n][r] * invR * invC[n], 0.f);
    }
  }
  psum *= wgt;
  for (int off = 32; off; off >>= 1) psum += __shfl_down(psum, off, 64);
  if (lane == 0) r4[wave] = psum;
  __syncthreads();
  if (tid == 0) atomicAdd(acc + 2, r4[0] + r4[1] + r4[2] + r4[3]);
}

// ---------------------------------------------------------------------------
__global__ void finalize_kernel(const float* __restrict__ acc, float* __restrict__ out) {
  // bce = (softplus_sum - corner_score_sum)/(B*H*W); + relu_sum/(B*N*N)
  out[0] = (acc[0] - acc[1]) * (1.f / 2359296.f) + acc[2] * (1.f / 67108864.f);
}

extern "C" void kernel_launch(void* const* d_in, const int* in_sizes, int n_in,
                              void* d_out, int out_size, void* d_ws, size_t ws_size,
                              hipStream_t stream) {
  (void)in_sizes; (void)n_in; (void)out_size; (void)ws_size;
  const float* desc = (const float*)d_in[0];
  // d_in[1] = scores (unused by the reference)
  const float* sd = (const float*)d_in[2];
  const float* imgs = (const float*)d_in[3];
  float* out = (float*)d_out;

  char* w = (char*)d_ws;
  float* acc = (float*)w;                                  // [0]=softplus,[1]=corner,[2]=relu
  float* resp = (float*)(w + OFF_RESP);
  float* cval = (float*)(w + OFF_CVAL);
  unsigned* cpos = (unsigned*)(w + OFF_CPOS);
  unsigned short* descB = (unsigned short*)(w + OFF_DESCB);
  float* invn = (float*)(w + OFF_INV);

  hipMemsetAsync(d_ws, 0, 64, stream);  // zero accumulators (ws is re-poisoned)

  resp_kernel<<<2304, 256, 0, stream>>>(imgs, resp);
  nms_kernel<<<576, 256, 0, stream>>>(resp, cval, cpos);
  topk_kernel<<<16, 512, 0, stream>>>(cval, cpos, sd, acc);
  softplus_kernel<<<2304, 256, 0, stream>>>((const float4*)sd, acc);
  prep_desc_kernel<<<8192, 256, 0, stream>>>(desc, descB, invn);
  gemm_relu_kernel<<<2176, 256, 0, stream>>>(descB, invn, acc);
  finalize_kernel<<<1, 1, 0, stream>>>(acc, out);
}

// Round 2
// 275.327 us; speedup vs baseline: 1.4288x; 1.4288x over previous
//
#include <hip/hip_runtime.h>

#define H 384
#define W 384
#define HWSZ (H * W)
#define NB 16
#define ND 2048
#define DD 256

// workspace byte offsets (all 256-aligned)
#define OFF_RESP  256
#define OFF_CVAL  9437440
#define OFF_CPOS  9584896
#define OFF_DESCB 9732352
#define OFF_INV   26509568
#define OFF_PSOFT 26640640   // 576 floats
#define OFF_PGEMM 26643200   // 2176 floats
#define OFF_PCORN 26652160   // 16 floats

__device__ __forceinline__ int clampi(int v) { return v < 0 ? 0 : (v > 383 ? 383 : v); }
__device__ __forceinline__ int refl(int v) { return v < 0 ? -v : (v >= 384 ? 766 - v : v); }

__device__ __forceinline__ unsigned short f2bf(float f) {
  unsigned u = __float_as_uint(f);
  return (unsigned short)((u + 0x7FFFu + ((u >> 16) & 1u)) >> 16);
}

// ---------------------------------------------------------------------------
// Fused: grayscale -> sobel(edge pad) -> products -> separable 7x7 gauss
// (reflect pad) -> GFTT min-eigenvalue response. One 32x32 output tile/block.
// ---------------------------------------------------------------------------
__global__ __launch_bounds__(256) void resp_kernel(const float* __restrict__ imgs,
                                                   float* __restrict__ resp) {
  const float GW[7] = {0.0044330482f, 0.0540055826f, 0.2420362294f, 0.3990502160f,
                       0.2420362294f, 0.0540055826f, 0.0044330482f};
  __shared__ float gl[40][41];
  __shared__ float p0[38][39], p1[38][39], p2[38][39];
  __shared__ float t0[38][33], t1[38][33], t2[38][33];

  int bid = blockIdx.x;
  int b = bid / 144;
  int t = bid % 144;
  int Y0 = (t / 12) * 32, X0 = (t % 12) * 32;
  const float* ib = imgs + (size_t)b * 3 * HWSZ;

  // gray tile with 4-halo, edge-clamped (clamp also serves sobel's edge pad)
  for (int i = threadIdx.x; i < 1600; i += 256) {
    int r = i / 40, c = i % 40;
    int gy = clampi(Y0 - 4 + r), gx = clampi(X0 - 4 + c);
    const float* p = ib + gy * W + gx;
    gl[r][c] = 0.299f * p[0] + 0.587f * p[HWSZ] + 0.114f * p[2 * HWSZ];
  }
  __syncthreads();

  // structure-tensor products at reflect-mapped coordinates (handles gauss pad)
  for (int i = threadIdx.x; i < 1444; i += 256) {
    int r = i / 38, c = i % 38;
    int py = refl(Y0 - 3 + r), px = refl(X0 - 3 + c);
    int ym = clampi(py - 1) - (Y0 - 4), y0 = py - (Y0 - 4), yp = clampi(py + 1) - (Y0 - 4);
    int xm = clampi(px - 1) - (X0 - 4), x0 = px - (X0 - 4), xp = clampi(px + 1) - (X0 - 4);
    float a = gl[ym][xm], bb = gl[ym][x0], cc = gl[ym][xp];
    float d = gl[y0][xm], e = gl[y0][xp];
    float f = gl[yp][xm], g = gl[yp][x0], h = gl[yp][xp];
    float dx = 0.125f * ((cc - a) + 2.f * (e - d) + (h - f));
    float dy = 0.125f * ((f - a) + 2.f * (g - bb) + (h - cc));
    p0[r][c] = dx * dx;
    p1[r][c] = dy * dy;
    p2[r][c] = dx * dy;
  }
  __syncthreads();

  // horizontal gaussian
  for (int i = threadIdx.x; i < 1216; i += 256) {
    int r = i / 32, c = i % 32;
    float s0 = 0.f, s1 = 0.f, s2 = 0.f;
#pragma unroll
    for (int j = 0; j < 7; j++) {
      s0 += GW[j] * p0[r][c + j];
      s1 += GW[j] * p1[r][c + j];
      s2 += GW[j] * p2[r][c + j];
    }
    t0[r][c] = s0; t1[r][c] = s1; t2[r][c] = s2;
  }
  __syncthreads();

  // vertical gaussian + GFTT response
  for (int i = threadIdx.x; i < 1024; i += 256) {
    int r = i / 32, c = i % 32;
    float s0 = 0.f, s1 = 0.f, s2 = 0.f;
#pragma unroll
    for (int j = 0; j < 7; j++) {
      s0 += GW[j] * t0[r + j][c];
      s1 += GW[j] * t1[r + j][c];
      s2 += GW[j] * t2[r + j][c];
    }
    float tr = s0 + s1;
    float det = s0 * s1 - s2 * s2;
    float disc = tr * tr - 4.f * det;
    float rv = 0.5f * (tr - sqrtf(fabsf(disc)));
    resp[(size_t)b * HWSZ + (Y0 + r) * W + (X0 + c)] = rv;
  }
}

// ---------------------------------------------------------------------------
// 5x5 NMS (-inf border) + per-8x8-block max candidate extraction.
// ---------------------------------------------------------------------------
__global__ __launch_bounds__(256) void nms_kernel(const float* __restrict__ resp,
                                                  float* __restrict__ cval,
                                                  unsigned* __restrict__ cpos) {
  __shared__ float rl[68][69];
  __shared__ float nl[64][65];
  int bid = blockIdx.x;
  int b = bid / 36;
  int t = bid % 36;
  int Y0 = (t / 6) * 64, X0 = (t % 6) * 64;
  const float* rb = resp + (size_t)b * HWSZ;

  for (int i = threadIdx.x; i < 68 * 68; i += 256) {
    int r = i / 68, c = i % 68;
    int gy = Y0 - 2 + r, gx = X0 - 2 + c;
    float v = -INFINITY;
    if (gy >= 0 && gy < H && gx >= 0 && gx < W) v = rb[gy * W + gx];
    rl[r][c] = v;
  }
  __syncthreads();

  for (int i = threadIdx.x; i < 4096; i += 256) {
    int r = i / 64, c = i % 64;
    float m = -INFINITY;
#pragma unroll
    for (int dr = 0; dr < 5; dr++)
#pragma unroll
      for (int dc = 0; dc < 5; dc++) m = fmaxf(m, rl[r + dr][c + dc]);
    float v = rl[r + 2][c + 2];
    nl[r][c] = (v == m) ? v : 0.f;
  }
  __syncthreads();

  if (threadIdx.x < 64) {
    int bi = threadIdx.x / 8, bj = threadIdx.x % 8;
    float bv = 0.f;
    unsigned bp = 0;
    for (int rr = 0; rr < 8; rr++)
      for (int cc = 0; cc < 8; cc++) {
        float v = nl[bi * 8 + rr][bj * 8 + cc];
        if (v > bv) { bv = v; bp = (unsigned)((Y0 + bi * 8 + rr) * W + (X0 + bj * 8 + cc)); }
      }
    int ci = b * 2304 + (Y0 / 8 + bi) * 48 + (X0 / 8 + bj);
    cval[ci] = bv;
    cpos[ci] = bp;
  }
}

// ---------------------------------------------------------------------------
// Per-batch top-200 (bitonic sort of 4096 packed keys) -> sum scores_dense at
// selected positive positions -> pcorn[b]. Key = valbits<<32 | ~pos.
// ---------------------------------------------------------------------------
__global__ __launch_bounds__(512) void topk_kernel(const float* __restrict__ cval,
                                                   const unsigned* __restrict__ cpos,
                                                   const float* __restrict__ sd,
                                                   float* __restrict__ pcorn) {
  __shared__ unsigned long long keys[4096];
  __shared__ float r8[8];
  int b = blockIdx.x;
  for (int i = threadIdx.x; i < 4096; i += 512) {
    unsigned long long k = 0ull;
    if (i < 2304) {
      float v = cval[b * 2304 + i];
      if (v > 0.f)
        k = ((unsigned long long)__float_as_uint(v) << 32) |
            (unsigned long long)(0xFFFFFFFFu - cpos[b * 2304 + i]);
    }
    keys[i] = k;
  }
  __syncthreads();
  for (int kk = 2; kk <= 4096; kk <<= 1) {
    for (int j = kk >> 1; j > 0; j >>= 1) {
      for (int i = threadIdx.x; i < 4096; i += 512) {
        int ixj = i ^ j;
        if (ixj > i) {
          unsigned long long a = keys[i], c = keys[ixj];
          bool up = ((i & kk) == 0);
          if (up ? (a > c) : (a < c)) { keys[i] = c; keys[ixj] = a; }
        }
      }
      __syncthreads();
    }
  }
  float s = 0.f;
  if (threadIdx.x < 200) {
    unsigned long long k = keys[4095 - threadIdx.x];
    if ((k >> 32) != 0ull) {
      unsigned p = 0xFFFFFFFFu - (unsigned)(k & 0xFFFFFFFFull);
      s = sd[(size_t)b * HWSZ + p];
    }
  }
  for (int off = 32; off; off >>= 1) s += __shfl_down(s, off, 64);
  if ((threadIdx.x & 63) == 0) r8[threadIdx.x >> 6] = s;
  __syncthreads();
  if (threadIdx.x == 0) {
    float tt = 0.f;
    for (int i = 0; i < 8; i++) tt += r8[i];
    pcorn[b] = tt;
  }
}

// ---------------------------------------------------------------------------
// Sum of softplus(scores_dense) -> per-block partials (NO single-address
// atomics — R1 showed 9216 same-address atomicAdds cost 120us).
// 576 blocks x 256 threads x 4 float4 = 589824 float4s exactly.
// ---------------------------------------------------------------------------
__global__ __launch_bounds__(256) void softplus_kernel(const float4* __restrict__ sd,
                                                       float* __restrict__ psoft) {
  __shared__ float r4[4];
  float s = 0.f;
  int base = blockIdx.x * 256 + threadIdx.x;
#pragma unroll
  for (int it = 0; it < 4; it++) {
    float4 v = sd[base + it * 147456];
    s += fmaxf(v.x, 0.f) + log1pf(expf(-fabsf(v.x))) +
         fmaxf(v.y, 0.f) + log1pf(expf(-fabsf(v.y))) +
         fmaxf(v.z, 0.f) + log1pf(expf(-fabsf(v.z))) +
         fmaxf(v.w, 0.f) + log1pf(expf(-fabsf(v.w)));
  }
  for (int off = 32; off; off >>= 1) s += __shfl_down(s, off, 64);
  if ((threadIdx.x & 63) == 0) r4[threadIdx.x >> 6] = s;
  __syncthreads();
  if (threadIdx.x == 0) psoft[blockIdx.x] = r4[0] + r4[1] + r4[2] + r4[3];
}

// ---------------------------------------------------------------------------
// Descriptor prep: fp32 -> bf16 copy + per-row inverse norm (fp32 norms).
// ---------------------------------------------------------------------------
__global__ __launch_bounds__(256) void prep_desc_kernel(const float* __restrict__ desc,
                                                        unsigned short* __restrict__ descB,
                                                        float* __restrict__ invn) {
  int wave = threadIdx.x >> 6, lane = threadIdx.x & 63;
  int row = blockIdx.x * 4 + wave;
  const float4* src = (const float4*)(desc + (size_t)row * DD);
  float4 v = src[lane];
  ushort4 u;
  u.x = f2bf(v.x); u.y = f2bf(v.y); u.z = f2bf(v.z); u.w = f2bf(v.w);
  ((ushort4*)(descB + (size_t)row * DD))[lane] = u;
  float ss = v.x * v.x + v.y * v.y + v.z * v.z + v.w * v.w;
  for (int off = 32; off; off >>= 1) ss += __shfl_down(ss, off, 64);
  if (lane == 0) invn[row] = 1.f / fmaxf(sqrtf(ss), 1e-4f);
}

// ---------------------------------------------------------------------------
// Symmetric batched GEMM (A·A^T) with fused relu-sum epilogue.
// 128x128 tiles, BK=64, 16x16x32 bf16 MFMA, global_load_lds width-16 staging.
// Only upper-triangular tile pairs (ti<=tj), weight 2 off-diagonal.
// Per-block partial written to pgemm[bx] (no atomics).
// ---------------------------------------------------------------------------
typedef __bf16 bf16x8 __attribute__((ext_vector_type(8)));
typedef float f32x4 __attribute__((ext_vector_type(4)));

__device__ __forceinline__ void load_lds16(const void* g, void* l) {
  __builtin_amdgcn_global_load_lds((const __attribute__((address_space(1))) void*)g,
                                   (__attribute__((address_space(3))) void*)l, 16, 0, 0);
}

__global__ __launch_bounds__(256) void gemm_relu_kernel(const unsigned short* __restrict__ descB,
                                                        const float* __restrict__ invn,
                                                        float* __restrict__ pgemm) {
  int bx = blockIdx.x;
  int batch = bx / 136;
  int rem = bx % 136;
  int ti = 0, rowlen = 16;
  while (rem >= rowlen) { rem -= rowlen; rowlen--; ti++; }
  int tj = ti + rem;

  const unsigned short* Ab = descB + (size_t)batch * ND * DD;
  const float* inv = invn + batch * ND;
  int I0 = ti * 128, J0 = tj * 128;

  __shared__ unsigned short lA[128 * 64];
  __shared__ unsigned short lB[128 * 64];
  __shared__ float r4[4];

  int tid = threadIdx.x;
  int wave = tid >> 6, lane = tid & 63;
  int rm = lane & 15, kq = lane >> 4;
  int wr = wave >> 1, wc = wave & 1;
  int lrow = lane >> 3, lcol = (lane & 7) * 8;

  f32x4 accf[4][4];
#pragma unroll
  for (int m = 0; m < 4; m++)
#pragma unroll
    for (int n = 0; n < 4; n++) accf[m][n] = (f32x4){0.f, 0.f, 0.f, 0.f};

  for (int k0 = 0; k0 < DD; k0 += 64) {
#pragma unroll
    for (int q = 0; q < 4; q++) {
      int chunk = wave * 4 + q;
      load_lds16(Ab + (size_t)(I0 + chunk * 8 + lrow) * DD + k0 + lcol, lA + chunk * 512);
      load_lds16(Ab + (size_t)(J0 + chunk * 8 + lrow) * DD + k0 + lcol, lB + chunk * 512);
    }
    __syncthreads();
#pragma unroll
    for (int kk = 0; kk < 64; kk += 32) {
      bf16x8 af[4], bfr[4];
      int koff = kk + kq * 8;
#pragma unroll
      for (int m = 0; m < 4; m++)
        af[m] = *reinterpret_cast<const bf16x8*>(lA + (wr * 64 + m * 16 + rm) * 64 + koff);
#pragma unroll
      for (int n = 0; n < 4; n++)
        bfr[n] = *reinterpret_cast<const bf16x8*>(lB + (wc * 64 + n * 16 + rm) * 64 + koff);
#pragma unroll
      for (int m = 0; m < 4; m++)
#pragma unroll
        for (int n = 0; n < 4; n++)
          accf[m][n] = __builtin_amdgcn_mfma_f32_16x16x32_bf16(af[m], bfr[n], accf[m][n], 0, 0, 0);
    }
    __syncthreads();
  }

  float wgt = (ti == tj) ? 1.f : 2.f;
  float invC[4];
#pragma unroll
  for (int n = 0; n < 4; n++) invC[n] = inv[J0 + wc * 64 + n * 16 + rm];
  float psum = 0.f;
#pragma unroll
  for (int m = 0; m < 4; m++) {
#pragma unroll
    for (int r = 0; r < 4; r++) {
      float invR = inv[I0 + wr * 64 + m * 16 + kq * 4 + r];
#pragma unroll
      for (int n = 0; n < 4; n++) psum += fmaxf(accf[m][n][r] * invR * invC[n], 0.f);
    }
  }
  psum *= wgt;
  for (int off = 32; off; off >>= 1) psum += __shfl_down(psum, off, 64);
  if (lane == 0) r4[wave] = psum;
  __syncthreads();
  if (tid == 0) pgemm[bx] = r4[0] + r4[1] + r4[2] + r4[3];
}

// ---------------------------------------------------------------------------
// Final reduction over all partial arrays -> out[0].
// ---------------------------------------------------------------------------
__global__ __launch_bounds__(256) void finalize_kernel(const float* __restrict__ psoft,
                                                       const float* __restrict__ pcorn,
                                                       const float* __restrict__ pgemm,
                                                       float* __restrict__ out) {
  __shared__ float r4[4];
  float bce = 0.f;
  for (int i = threadIdx.x; i < 576; i += 256) bce += psoft[i];
  if (threadIdx.x < 16) bce -= pcorn[threadIdx.x];
  float g = 0.f;
  for (int i = threadIdx.x; i < 2176; i += 256) g += pgemm[i];
  float t = bce * (1.f / 2359296.f) + g * (1.f / 67108864.f);
  for (int off = 32; off; off >>= 1) t += __shfl_down(t, off, 64);
  if ((threadIdx.x & 63) == 0) r4[threadIdx.x >> 6] = t;
  __syncthreads();
  if (threadIdx.x == 0) out[0] = r4[0] + r4[1] + r4[2] + r4[3];
}

extern "C" void kernel_launch(void* const* d_in, const int* in_sizes, int n_in,
                              void* d_out, int out_size, void* d_ws, size_t ws_size,
                              hipStream_t stream) {
  (void)in_sizes; (void)n_in; (void)out_size; (void)ws_size;
  const float* desc = (const float*)d_in[0];
  // d_in[1] = scores (unused by the reference)
  const float* sd = (const float*)d_in[2];
  const float* imgs = (const float*)d_in[3];
  float* out = (float*)d_out;

  char* w = (char*)d_ws;
  float* resp = (float*)(w + OFF_RESP);
  float* cval = (float*)(w + OFF_CVAL);
  unsigned* cpos = (unsigned*)(w + OFF_CPOS);
  unsigned short* descB = (unsigned short*)(w + OFF_DESCB);
  float* invn = (float*)(w + OFF_INV);
  float* psoft = (float*)(w + OFF_PSOFT);
  float* pgemm = (float*)(w + OFF_PGEMM);
  float* pcorn = (float*)(w + OFF_PCORN);

  resp_kernel<<<2304, 256, 0, stream>>>(imgs, resp);
  nms_kernel<<<576, 256, 0, stream>>>(resp, cval, cpos);
  topk_kernel<<<16, 512, 0, stream>>>(cval, cpos, sd, pcorn);
  softplus_kernel<<<576, 256, 0, stream>>>((const float4*)sd, psoft);
  prep_desc_kernel<<<8192, 256, 0, stream>>>(desc, descB, invn);
  gemm_relu_kernel<<<2176, 256, 0, stream>>>(descB, invn, pgemm);
  finalize_kernel<<<1, 256, 0, stream>>>(psoft, pcorn, pgemm, out);
}

// Round 3
// 191.801 us; speedup vs baseline: 2.0510x; 1.4355x over previous
//
#include <hip/hip_runtime.h>

#define H 384
#define W 384
#define HWSZ (H * W)
#define NB 16
#define ND 2048
#define DD 256

// workspace byte offsets (all 256-aligned)
#define OFF_RESP  256
#define OFF_CVAL  9437440
#define OFF_CPOS  9584896
#define OFF_DESCB 9732352
#define OFF_INV   26509568
#define OFF_PSOFT 26640640   // 576 floats
#define OFF_PGEMM 26643200   // 2176 floats
#define OFF_PCORN 26652160   // 16 floats

__device__ __forceinline__ int clampi(int v) { return v < 0 ? 0 : (v > 383 ? 383 : v); }
__device__ __forceinline__ int refl(int v) { return v < 0 ? -v : (v >= 384 ? 766 - v : v); }

__device__ __forceinline__ unsigned short f2bf(float f) {
  unsigned u = __float_as_uint(f);
  return (unsigned short)((u + 0x7FFFu + ((u >> 16) & 1u)) >> 16);
}

// ---------------------------------------------------------------------------
// Fused: grayscale -> sobel(edge pad) -> products -> separable 7x7 gauss
// (reflect pad) -> GFTT min-eigenvalue response. One 32x32 output tile/block.
// ---------------------------------------------------------------------------
__global__ __launch_bounds__(256) void resp_kernel(const float* __restrict__ imgs,
                                                   float* __restrict__ resp) {
  const float GW[7] = {0.0044330482f, 0.0540055826f, 0.2420362294f, 0.3990502160f,
                       0.2420362294f, 0.0540055826f, 0.0044330482f};
  __shared__ float gl[40][41];
  __shared__ float p0[38][39], p1[38][39], p2[38][39];
  __shared__ float t0[38][33], t1[38][33], t2[38][33];

  int bid = blockIdx.x;
  int b = bid / 144;
  int t = bid % 144;
  int Y0 = (t / 12) * 32, X0 = (t % 12) * 32;
  const float* ib = imgs + (size_t)b * 3 * HWSZ;

  for (int i = threadIdx.x; i < 1600; i += 256) {
    int r = i / 40, c = i % 40;
    int gy = clampi(Y0 - 4 + r), gx = clampi(X0 - 4 + c);
    const float* p = ib + gy * W + gx;
    gl[r][c] = 0.299f * p[0] + 0.587f * p[HWSZ] + 0.114f * p[2 * HWSZ];
  }
  __syncthreads();

  for (int i = threadIdx.x; i < 1444; i += 256) {
    int r = i / 38, c = i % 38;
    int py = refl(Y0 - 3 + r), px = refl(X0 - 3 + c);
    int ym = clampi(py - 1) - (Y0 - 4), y0 = py - (Y0 - 4), yp = clampi(py + 1) - (Y0 - 4);
    int xm = clampi(px - 1) - (X0 - 4), x0 = px - (X0 - 4), xp = clampi(px + 1) - (X0 - 4);
    float a = gl[ym][xm], bb = gl[ym][x0], cc = gl[ym][xp];
    float d = gl[y0][xm], e = gl[y0][xp];
    float f = gl[yp][xm], g = gl[yp][x0], h = gl[yp][xp];
    float dx = 0.125f * ((cc - a) + 2.f * (e - d) + (h - f));
    float dy = 0.125f * ((f - a) + 2.f * (g - bb) + (h - cc));
    p0[r][c] = dx * dx;
    p1[r][c] = dy * dy;
    p2[r][c] = dx * dy;
  }
  __syncthreads();

  for (int i = threadIdx.x; i < 1216; i += 256) {
    int r = i / 32, c = i % 32;
    float s0 = 0.f, s1 = 0.f, s2 = 0.f;
#pragma unroll
    for (int j = 0; j < 7; j++) {
      s0 += GW[j] * p0[r][c + j];
      s1 += GW[j] * p1[r][c + j];
      s2 += GW[j] * p2[r][c + j];
    }
    t0[r][c] = s0; t1[r][c] = s1; t2[r][c] = s2;
  }
  __syncthreads();

  for (int i = threadIdx.x; i < 1024; i += 256) {
    int r = i / 32, c = i % 32;
    float s0 = 0.f, s1 = 0.f, s2 = 0.f;
#pragma unroll
    for (int j = 0; j < 7; j++) {
      s0 += GW[j] * t0[r + j][c];
      s1 += GW[j] * t1[r + j][c];
      s2 += GW[j] * t2[r + j][c];
    }
    float tr = s0 + s1;
    float det = s0 * s1 - s2 * s2;
    float disc = tr * tr - 4.f * det;
    float rv = 0.5f * (tr - sqrtf(fabsf(disc)));
    resp[(size_t)b * HWSZ + (Y0 + r) * W + (X0 + c)] = rv;
  }
}

// ---------------------------------------------------------------------------
// 5x5 NMS (-inf border) + per-8x8-block max candidate extraction.
// ---------------------------------------------------------------------------
__global__ __launch_bounds__(256) void nms_kernel(const float* __restrict__ resp,
                                                  float* __restrict__ cval,
                                                  unsigned* __restrict__ cpos) {
  __shared__ float rl[68][69];
  __shared__ float nl[64][65];
  int bid = blockIdx.x;
  int b = bid / 36;
  int t = bid % 36;
  int Y0 = (t / 6) * 64, X0 = (t % 6) * 64;
  const float* rb = resp + (size_t)b * HWSZ;

  for (int i = threadIdx.x; i < 68 * 68; i += 256) {
    int r = i / 68, c = i % 68;
    int gy = Y0 - 2 + r, gx = X0 - 2 + c;
    float v = -INFINITY;
    if (gy >= 0 && gy < H && gx >= 0 && gx < W) v = rb[gy * W + gx];
    rl[r][c] = v;
  }
  __syncthreads();

  for (int i = threadIdx.x; i < 4096; i += 256) {
    int r = i / 64, c = i % 64;
    float m = -INFINITY;
#pragma unroll
    for (int dr = 0; dr < 5; dr++)
#pragma unroll
      for (int dc = 0; dc < 5; dc++) m = fmaxf(m, rl[r + dr][c + dc]);
    float v = rl[r + 2][c + 2];
    nl[r][c] = (v == m) ? v : 0.f;
  }
  __syncthreads();

  if (threadIdx.x < 64) {
    int bi = threadIdx.x / 8, bj = threadIdx.x % 8;
    float bv = 0.f;
    unsigned bp = 0;
    for (int rr = 0; rr < 8; rr++)
      for (int cc = 0; cc < 8; cc++) {
        float v = nl[bi * 8 + rr][bj * 8 + cc];
        if (v > bv) { bv = v; bp = (unsigned)((Y0 + bi * 8 + rr) * W + (X0 + bj * 8 + cc)); }
      }
    int ci = b * 2304 + (Y0 / 8 + bi) * 48 + (X0 / 8 + bj);
    cval[ci] = bv;
    cpos[ci] = bp;
  }
}

// ---------------------------------------------------------------------------
// Per-batch top-200 via byte-wise radix-select (replaces 78-pass bitonic sort
// that cost 96us at 1.4% occupancy). Positive floats order like their uint
// bits. 4 rounds of 256-bin histogram find the exact 32-bit value V* of the
// K-th largest candidate (K=min(200,#pos)); sum sd at positions with
// val > V*, plus the lowest-position subset of val == V* (jax top_k
// tie-break). One block per batch, 256 threads, 9 candidates/thread.
// ---------------------------------------------------------------------------
__global__ __launch_bounds__(256) void topk_kernel(const float* __restrict__ cval,
                                                   const unsigned* __restrict__ cpos,
                                                   const float* __restrict__ sd,
                                                   float* __restrict__ pcorn) {
  __shared__ int hist[256];
  __shared__ int pick[2];        // [0]=bin T, [1]=G(T)
  __shared__ unsigned eqpos[256];
  __shared__ int eqcnt;
  __shared__ float rf[4];
  __shared__ int ri[4];

  int b = blockIdx.x;
  int t = threadIdx.x;
  int lane = t & 63;

  unsigned bits[9], pos[9];
#pragma unroll
  for (int q = 0; q < 9; q++) {
    int i = t + q * 256;
    unsigned vb = 0, p = 0;
    if (i < 2304) {
      float v = cval[b * 2304 + i];
      if (v > 0.f) { vb = __float_as_uint(v); p = cpos[b * 2304 + i]; }
    }
    bits[q] = vb; pos[q] = p;
  }

  // count positives -> K = min(200, P)
  int P = 0;
#pragma unroll
  for (int q = 0; q < 9; q++) P += (bits[q] != 0u);
  for (int off = 32; off; off >>= 1) P += __shfl_down(P, off, 64);
  if (lane == 0) ri[t >> 6] = P;
  __syncthreads();
  int Ptot = ri[0] + ri[1] + ri[2] + ri[3];
  if (Ptot == 0) { if (t == 0) pcorn[b] = 0.f; return; }
  int K = Ptot < 200 ? Ptot : 200;

  unsigned prefix = 0;
  int krem = K;
  for (int shift = 24; shift >= 0; shift -= 8) {
    hist[t] = 0;
    __syncthreads();
#pragma unroll
    for (int q = 0; q < 9; q++) {
      if (bits[q] != 0u &&
          (shift == 24 || (bits[q] >> (shift + 8)) == (prefix >> (shift + 8))))
        atomicAdd(&hist[(bits[q] >> shift) & 0xFF], 1);
    }
    __syncthreads();
    // wave 0: suffix counts over 256 bins (4 bins/lane) and pick crossing bin
    if (t < 64) {
      int h0 = hist[4 * t], h1 = hist[4 * t + 1], h2 = hist[4 * t + 2], h3 = hist[4 * t + 3];
      int tot = h0 + h1 + h2 + h3;
      int acc = tot;
      for (int d = 1; d < 64; d <<= 1) {
        int o = __shfl_down(acc, d, 64);
        if (t + d < 64) acc += o;
      }
      int excl = acc - tot;  // count in bins above this lane's group
      int G3 = excl, G2 = excl + h3, G1 = excl + h3 + h2, G0 = excl + h3 + h2 + h1;
      if (G0 < krem && G0 + h0 >= krem) { pick[0] = 4 * t;     pick[1] = G0; }
      if (G1 < krem && G1 + h1 >= krem) { pick[0] = 4 * t + 1; pick[1] = G1; }
      if (G2 < krem && G2 + h2 >= krem) { pick[0] = 4 * t + 2; pick[1] = G2; }
      if (G3 < krem && G3 + h3 >= krem) { pick[0] = 4 * t + 3; pick[1] = G3; }
    }
    __syncthreads();
    prefix |= ((unsigned)pick[0]) << shift;
    krem -= pick[1];
    __syncthreads();
  }

  // prefix == V*, krem == #equals to include (>=1)
  if (t == 0) eqcnt = 0;
  __syncthreads();
  float s = 0.f;
#pragma unroll
  for (int q = 0; q < 9; q++) {
    if (bits[q] > prefix) s += sd[(size_t)b * HWSZ + pos[q]];
    else if (bits[q] != 0u && bits[q] == prefix) {
      int idx = atomicAdd(&eqcnt, 1);
      if (idx < 256) eqpos[idx] = pos[q];
    }
  }
  __syncthreads();
  int m = eqcnt;
  if (m <= krem) {
    if (t < m) s += sd[(size_t)b * HWSZ + eqpos[t]];
  } else {
    int mm = m < 256 ? m : 256;
    if (t < mm) {
      unsigned p = eqpos[t];
      int rank = 0;
      for (int u = 0; u < mm; u++) rank += (eqpos[u] < p);
      if (rank < krem) s += sd[(size_t)b * HWSZ + p];
    }
  }
  // block reduce s
  for (int off = 32; off; off >>= 1) s += __shfl_down(s, off, 64);
  if (lane == 0) rf[t >> 6] = s;
  __syncthreads();
  if (t == 0) pcorn[b] = rf[0] + rf[1] + rf[2] + rf[3];
}

// ---------------------------------------------------------------------------
// Sum of softplus(scores_dense) -> per-block partials.
// ---------------------------------------------------------------------------
__global__ __launch_bounds__(256) void softplus_kernel(const float4* __restrict__ sd,
                                                       float* __restrict__ psoft) {
  __shared__ float r4[4];
  float s = 0.f;
  int base = blockIdx.x * 256 + threadIdx.x;
#pragma unroll
  for (int it = 0; it < 4; it++) {
    float4 v = sd[base + it * 147456];
    s += fmaxf(v.x, 0.f) + log1pf(expf(-fabsf(v.x))) +
         fmaxf(v.y, 0.f) + log1pf(expf(-fabsf(v.y))) +
         fmaxf(v.z, 0.f) + log1pf(expf(-fabsf(v.z))) +
         fmaxf(v.w, 0.f) + log1pf(expf(-fabsf(v.w)));
  }
  for (int off = 32; off; off >>= 1) s += __shfl_down(s, off, 64);
  if ((threadIdx.x & 63) == 0) r4[threadIdx.x >> 6] = s;
  __syncthreads();
  if (threadIdx.x == 0) psoft[blockIdx.x] = r4[0] + r4[1] + r4[2] + r4[3];
}

// ---------------------------------------------------------------------------
// Descriptor prep: fp32 -> bf16 copy + per-row inverse norm (fp32 norms).
// ---------------------------------------------------------------------------
__global__ __launch_bounds__(256) void prep_desc_kernel(const float* __restrict__ desc,
                                                        unsigned short* __restrict__ descB,
                                                        float* __restrict__ invn) {
  int wave = threadIdx.x >> 6, lane = threadIdx.x & 63;
  int row = blockIdx.x * 4 + wave;
  const float4* src = (const float4*)(desc + (size_t)row * DD);
  float4 v = src[lane];
  ushort4 u;
  u.x = f2bf(v.x); u.y = f2bf(v.y); u.z = f2bf(v.z); u.w = f2bf(v.w);
  ((ushort4*)(descB + (size_t)row * DD))[lane] = u;
  float ss = v.x * v.x + v.y * v.y + v.z * v.z + v.w * v.w;
  for (int off = 32; off; off >>= 1) ss += __shfl_down(ss, off, 64);
  if (lane == 0) invn[row] = 1.f / fmaxf(sqrtf(ss), 1e-4f);
}

// ---------------------------------------------------------------------------
// Symmetric batched GEMM (A·A^T) with fused relu-sum epilogue.
// ---------------------------------------------------------------------------
typedef __bf16 bf16x8 __attribute__((ext_vector_type(8)));
typedef float f32x4 __attribute__((ext_vector_type(4)));

__device__ __forceinline__ void load_lds16(const void* g, void* l) {
  __builtin_amdgcn_global_load_lds((const __attribute__((address_space(1))) void*)g,
                                   (__attribute__((address_space(3))) void*)l, 16, 0, 0);
}

__global__ __launch_bounds__(256) void gemm_relu_kernel(const unsigned short* __restrict__ descB,
                                                        const float* __restrict__ invn,
                                                        float* __restrict__ pgemm) {
  int bx = blockIdx.x;
  int batch = bx / 136;
  int rem = bx % 136;
  int ti = 0, rowlen = 16;
  while (rem >= rowlen) { rem -= rowlen; rowlen--; ti++; }
  int tj = ti + rem;

  const unsigned short* Ab = descB + (size_t)batch * ND * DD;
  const float* inv = invn + batch * ND;
  int I0 = ti * 128, J0 = tj * 128;

  __shared__ unsigned short lA[128 * 64];
  __shared__ unsigned short lB[128 * 64];
  __shared__ float r4[4];

  int tid = threadIdx.x;
  int wave = tid >> 6, lane = tid & 63;
  int rm = lane & 15, kq = lane >> 4;
  int wr = wave >> 1, wc = wave & 1;
  int lrow = lane >> 3, lcol = (lane & 7) * 8;

  f32x4 accf[4][4];
#pragma unroll
  for (int m = 0; m < 4; m++)
#pragma unroll
    for (int n = 0; n < 4; n++) accf[m][n] = (f32x4){0.f, 0.f, 0.f, 0.f};

  for (int k0 = 0; k0 < DD; k0 += 64) {
#pragma unroll
    for (int q = 0; q < 4; q++) {
      int chunk = wave * 4 + q;
      load_lds16(Ab + (size_t)(I0 + chunk * 8 + lrow) * DD + k0 + lcol, lA + chunk * 512);
      load_lds16(Ab + (size_t)(J0 + chunk * 8 + lrow) * DD + k0 + lcol, lB + chunk * 512);
    }
    __syncthreads();
#pragma unroll
    for (int kk = 0; kk < 64; kk += 32) {
      bf16x8 af[4], bfr[4];
      int koff = kk + kq * 8;
#pragma unroll
      for (int m = 0; m < 4; m++)
        af[m] = *reinterpret_cast<const bf16x8*>(lA + (wr * 64 + m * 16 + rm) * 64 + koff);
#pragma unroll
      for (int n = 0; n < 4; n++)
        bfr[n] = *reinterpret_cast<const bf16x8*>(lB + (wc * 64 + n * 16 + rm) * 64 + koff);
#pragma unroll
      for (int m = 0; m < 4; m++)
#pragma unroll
        for (int n = 0; n < 4; n++)
          accf[m][n] = __builtin_amdgcn_mfma_f32_16x16x32_bf16(af[m], bfr[n], accf[m][n], 0, 0, 0);
    }
    __syncthreads();
  }

  float wgt = (ti == tj) ? 1.f : 2.f;
  float invC[4];
#pragma unroll
  for (int n = 0; n < 4; n++) invC[n] = inv[J0 + wc * 64 + n * 16 + rm];
  float psum = 0.f;
#pragma unroll
  for (int m = 0; m < 4; m++) {
#pragma unroll
    for (int r = 0; r < 4; r++) {
      float invR = inv[I0 + wr * 64 + m * 16 + kq * 4 + r];
#pragma unroll
      for (int n = 0; n < 4; n++) psum += fmaxf(accf[m][n][r] * invR * invC[n], 0.f);
    }
  }
  psum *= wgt;
  for (int off = 32; off; off >>= 1) psum += __shfl_down(psum, off, 64);
  if (lane == 0) r4[wave] = psum;
  __syncthreads();
  if (tid == 0) pgemm[bx] = r4[0] + r4[1] + r4[2] + r4[3];
}

// ---------------------------------------------------------------------------
// Final reduction over all partial arrays -> out[0].
// ---------------------------------------------------------------------------
__global__ __launch_bounds__(256) void finalize_kernel(const float* __restrict__ psoft,
                                                       const float* __restrict__ pcorn,
                                                       const float* __restrict__ pgemm,
                                                       float* __restrict__ out) {
  __shared__ float r4[4];
  float bce = 0.f;
  for (int i = threadIdx.x; i < 576; i += 256) bce += psoft[i];
  if (threadIdx.x < 16) bce -= pcorn[threadIdx.x];
  float g = 0.f;
  for (int i = threadIdx.x; i < 2176; i += 256) g += pgemm[i];
  float t = bce * (1.f / 2359296.f) + g * (1.f / 67108864.f);
  for (int off = 32; off; off >>= 1) t += __shfl_down(t, off, 64);
  if ((threadIdx.x & 63) == 0) r4[threadIdx.x >> 6] = t;
  __syncthreads();
  if (threadIdx.x == 0) out[0] = r4[0] + r4[1] + r4[2] + r4[3];
}

extern "C" void kernel_launch(void* const* d_in, const int* in_sizes, int n_in,
                              void* d_out, int out_size, void* d_ws, size_t ws_size,
                              hipStream_t stream) {
  (void)in_sizes; (void)n_in; (void)out_size; (void)ws_size;
  const float* desc = (const float*)d_in[0];
  const float* sd = (const float*)d_in[2];
  const float* imgs = (const float*)d_in[3];
  float* out = (float*)d_out;

  char* w = (char*)d_ws;
  float* resp = (float*)(w + OFF_RESP);
  float* cval = (float*)(w + OFF_CVAL);
  unsigned* cpos = (unsigned*)(w + OFF_CPOS);
  unsigned short* descB = (unsigned short*)(w + OFF_DESCB);
  float* invn = (float*)(w + OFF_INV);
  float* psoft = (float*)(w + OFF_PSOFT);
  float* pgemm = (float*)(w + OFF_PGEMM);
  float* pcorn = (float*)(w + OFF_PCORN);

  resp_kernel<<<2304, 256, 0, stream>>>(imgs, resp);
  nms_kernel<<<576, 256, 0, stream>>>(resp, cval, cpos);
  topk_kernel<<<16, 256, 0, stream>>>(cval, cpos, sd, pcorn);
  softplus_kernel<<<576, 256, 0, stream>>>((const float4*)sd, psoft);
  prep_desc_kernel<<<8192, 256, 0, stream>>>(desc, descB, invn);
  gemm_relu_kernel<<<2176, 256, 0, stream>>>(descB, invn, pgemm);
  finalize_kernel<<<1, 256, 0, stream>>>(psoft, pcorn, pgemm, out);
}